// Round 9
// baseline (572.499 us; speedup 1.0000x reference)
//
#include <hip/hip_runtime.h>

namespace {

typedef float v2f __attribute__((ext_vector_type(2)));

constexpr int T_SEQ = 2048;
constexpr int B_SZ  = 512;
constexpr int C_IN  = 8;
constexpr int H_SZ  = 20;
constexpr int P_LEN = 16;                 // steps per phase (barrier period)
constexpr int N_PH  = T_SEQ / P_LEN;      // 128 phases
constexpr int RING  = 2 * P_LEN;          // 32-slot rings (2 phases)
constexpr float LOG2E = 1.44269504088896340736f;

template<int S>
__device__ __forceinline__ float quad_bcast(float v) {
  return __int_as_float(__builtin_amdgcn_update_dpp(
      __float_as_int(v), __float_as_int(v), S * 0x55, 0xF, 0xF, true));
}

__device__ __forceinline__ v2f fma2(v2f a, v2f b, v2f c) {
  return __builtin_elementwise_fma(a, b, c);
}
__device__ __forceinline__ v2f zero2() { v2f r; r.x = 0.f; r.y = 0.f; return r; }

// 20-k recurrent dot, gate-set packed, 2 accumulators (same operand order as
// the builtin path -> bitwise-identical results). h[k] lives at lane 4k of ha
// (k<16) / lane 4(k-16) of hb. readlane pairs land in s[20:21]/s[22:23]
// (double-buffered); v_pk_fma_f32 op_sel broadcasts one 32-bit half of the
// SGPR pair to both result halves: 20 rl + 20 pk_fma vs 20 rl + 40 v_fma.
// Hazard: >=2 instructions between each readlane and its consuming pk_fma.
#define PKL(W, SP)  "v_pk_fma_f32 %0, " W ", " SP ", %0 op_sel:[0,0,0] op_sel_hi:[1,0,1]\n\t"
#define PKH(W, SP)  "v_pk_fma_f32 %1, " W ", " SP ", %1 op_sel:[0,1,0] op_sel_hi:[1,1,1]\n\t"
__device__ __forceinline__ void hdot20(v2f& A0, v2f& A1, float ha, float hb,
                                       const v2f (&w)[H_SZ]) {
  asm volatile(
    "v_readlane_b32 s20, %2, 0\n\t"
    "v_readlane_b32 s21, %2, 4\n\t"
    "v_readlane_b32 s22, %2, 8\n\t"
    "v_readlane_b32 s23, %2, 12\n\t"
    PKL("%4", "s[20:21]") PKH("%5", "s[20:21]")      // k0,k1
    "v_readlane_b32 s20, %2, 16\n\t"
    "v_readlane_b32 s21, %2, 20\n\t"
    PKL("%6", "s[22:23]") PKH("%7", "s[22:23]")      // k2,k3
    "v_readlane_b32 s22, %2, 24\n\t"
    "v_readlane_b32 s23, %2, 28\n\t"
    PKL("%8", "s[20:21]") PKH("%9", "s[20:21]")      // k4,k5
    "v_readlane_b32 s20, %2, 32\n\t"
    "v_readlane_b32 s21, %2, 36\n\t"
    PKL("%10", "s[22:23]") PKH("%11", "s[22:23]")    // k6,k7
    "v_readlane_b32 s22, %2, 40\n\t"
    "v_readlane_b32 s23, %2, 44\n\t"
    PKL("%12", "s[20:21]") PKH("%13", "s[20:21]")    // k8,k9
    "v_readlane_b32 s20, %2, 48\n\t"
    "v_readlane_b32 s21, %2, 52\n\t"
    PKL("%14", "s[22:23]") PKH("%15", "s[22:23]")    // k10,k11
    "v_readlane_b32 s22, %2, 56\n\t"
    "v_readlane_b32 s23, %2, 60\n\t"
    PKL("%16", "s[20:21]") PKH("%17", "s[20:21]")    // k12,k13
    "v_readlane_b32 s20, %3, 0\n\t"
    "v_readlane_b32 s21, %3, 4\n\t"
    PKL("%18", "s[22:23]") PKH("%19", "s[22:23]")    // k14,k15
    "v_readlane_b32 s22, %3, 8\n\t"
    "v_readlane_b32 s23, %3, 12\n\t"
    PKL("%20", "s[20:21]") PKH("%21", "s[20:21]")    // k16,k17
    PKL("%22", "s[22:23]") PKH("%23", "s[22:23]")    // k18,k19
    : "+v"(A0), "+v"(A1)
    : "v"(ha), "v"(hb),
      "v"(w[0]),  "v"(w[1]),  "v"(w[2]),  "v"(w[3]),  "v"(w[4]),
      "v"(w[5]),  "v"(w[6]),  "v"(w[7]),  "v"(w[8]),  "v"(w[9]),
      "v"(w[10]), "v"(w[11]), "v"(w[12]), "v"(w[13]), "v"(w[14]),
      "v"(w[15]), "v"(w[16]), "v"(w[17]), "v"(w[18]), "v"(w[19])
    : "s20", "s21", "s22", "s23");
}
#undef PKL
#undef PKH

// Elementwise activation on both gate sets: sigmoid (g!=2) / tanh (g==2).
__device__ __forceinline__ v2f act2(v2f a, float cm, float am, float ad) {
  float ex = __builtin_amdgcn_exp2f(a.x * cm);
  float ey = __builtin_amdgcn_exp2f(a.y * cm);
  float sx = __builtin_amdgcn_rcpf(1.0f + ex);
  float sy = __builtin_amdgcn_rcpf(1.0f + ey);
  v2f r; r.x = __fmaf_rn(sx, am, ad); r.y = __fmaf_rn(sy, am, ad);
  return r;
}

__device__ __forceinline__ float fast_tanh(float a) {
  float e = __builtin_amdgcn_exp2f(a * (-2.0f * LOG2E));
  float s = __builtin_amdgcn_rcpf(1.0f + e);
  return __fmaf_rn(s, 2.0f, -1.0f);
}

// 8 waves/block = 2 batches x 4 roles, forced 2 waves/SIMD.
// Wave->SIMD round-robin (i % 4) pairs each chain wave with a light feeder.
// Chain waves run at s_setprio(1) so they win issue arbitration.
__global__ __attribute__((amdgpu_flat_work_group_size(512, 512),
                          amdgpu_waves_per_eu(2, 2)))
void lstm2_4role(const float* __restrict__ x,
                 const float* __restrict__ Wih0, const float* __restrict__ Whh0,
                 const float* __restrict__ bih0, const float* __restrict__ bhh0,
                 const float* __restrict__ Wih1, const float* __restrict__ Whh1,
                 const float* __restrict__ bih1, const float* __restrict__ bhh1,
                 float* __restrict__ out)
{
  // Per-batch rings, [bb] = batch-in-block.
  __shared__ __align__(16) float hbuf[2][RING][H_SZ];   // L0 -> fy
  __shared__ __align__(16) v2f   ybuf[2][RING][64];     // fy -> L1 (16 KB each)
  __shared__ __align__(16) v2f   xsbuf[2][RING][64];    // fx -> L0 (16 KB each)
  __shared__ __align__(16) float xbuf[2][P_LEN * C_IN]; // fx-private x stage

  const int tid = threadIdx.x;
  const int wv  = tid >> 6;
  const int l   = tid & 63;
  const int bb  = (wv < 4) ? (wv >> 1) : ((wv - 4) >> 1);
  const int b   = blockIdx.x * 2 + bb;
  const int k1  = l >> 2;            // 0..15
  const int g   = l & 3;             // gate slot: 0=i 1=f 2=g 3=o
  const int k2  = 16 + (k1 & 3);     // 16..19 (replicated)
  const int j1  = g * H_SZ + k1;
  const int j2  = g * H_SZ + k2;

  const bool  isg = (g == 2);
  const float cm  = isg ? (-2.0f * LOG2E) : (-LOG2E);
  const float am  = isg ?  2.0f : 1.0f;
  const float ad  = isg ? -1.0f : 0.0f;

  if (wv < 4 && (wv & 1) == 0) {
    // ================= L0 recurrence chain (batch bb) =================
    __builtin_amdgcn_s_setprio(1);
    v2f wh[H_SZ];
#pragma unroll
    for (int k = 0; k < H_SZ; ++k) {
      wh[k].x = Whh0[j1 * H_SZ + k]; wh[k].y = Whh0[j2 * H_SZ + k];
    }
    v2f bias2; bias2.x = bih0[j1] + bhh0[j1]; bias2.y = bih0[j2] + bhh0[j2];

    float ha = 0.f, ca = 0.f, hb = 0.f, cb = 0.f;

    for (int s = 0; s <= N_PH + 2; ++s) {
      if (s >= 1 && s <= N_PH) {
        const int p0 = s - 1;
        v2f XsCur = xsbuf[bb][(p0 * P_LEN) & (RING - 1)][l];
        for (int j = 0; j < P_LEN; ++j) {
          const int n = p0 * P_LEN + j;
          const int slot = n & (RING - 1);
          v2f Xs = XsCur;
          if (j + 1 < P_LEN)
            XsCur = xsbuf[bb][(n + 1) & (RING - 1)][l];

          v2f A0 = bias2, A1 = Xs;
          hdot20(A0, A1, ha, hb, wh);
          v2f A = A0 + A1;

          v2f act = act2(A, cm, am, ad);
          float iv = quad_bcast<0>(act.x), fv = quad_bcast<1>(act.x);
          float gv = quad_bcast<2>(act.x), ov = quad_bcast<3>(act.x);
          ca = __fmaf_rn(fv, ca, iv * gv);
          ha = ov * fast_tanh(ca);
          iv = quad_bcast<0>(act.y); fv = quad_bcast<1>(act.y);
          gv = quad_bcast<2>(act.y); ov = quad_bcast<3>(act.y);
          cb = __fmaf_rn(fv, cb, iv * gv);
          hb = ov * fast_tanh(cb);

          if (g == 0) {
            hbuf[bb][slot][k1] = ha;
            if (k1 < 4) hbuf[bb][slot][16 + k1] = hb;
          }
        }
      }
      __syncthreads();
    }
  } else if (wv < 4) {
    // ================= L1 recurrence chain (batch bb, lags 3) ==============
    __builtin_amdgcn_s_setprio(1);
    v2f wq[H_SZ];
#pragma unroll
    for (int k = 0; k < H_SZ; ++k) {
      wq[k].x = Whh1[j1 * H_SZ + k]; wq[k].y = Whh1[j2 * H_SZ + k];
    }
    v2f bias2; bias2.x = bih1[j1] + bhh1[j1]; bias2.y = bih1[j2] + bhh1[j2];

    float ha = 0.f, ca = 0.f, hb = 0.f, cb = 0.f;
    float* op = out + b * H_SZ;

    for (int s = 0; s <= N_PH + 2; ++s) {
      if (s >= 3) {
        const int r = s - 3;
        v2f YsCur = ybuf[bb][(r * P_LEN) & (RING - 1)][l];
        for (int j = 0; j < P_LEN; ++j) {
          const int n = r * P_LEN + j;
          v2f Ys = YsCur;
          if (j + 1 < P_LEN)
            YsCur = ybuf[bb][(n + 1) & (RING - 1)][l];

          v2f Q0 = bias2, Q1 = Ys;
          hdot20(Q0, Q1, ha, hb, wq);
          v2f A = Q0 + Q1;

          v2f act = act2(A, cm, am, ad);
          float iv = quad_bcast<0>(act.x), fv = quad_bcast<1>(act.x);
          float gv = quad_bcast<2>(act.x), ov = quad_bcast<3>(act.x);
          ca = __fmaf_rn(fv, ca, iv * gv);
          ha = ov * fast_tanh(ca);
          iv = quad_bcast<0>(act.y); fv = quad_bcast<1>(act.y);
          gv = quad_bcast<2>(act.y); ov = quad_bcast<3>(act.y);
          cb = __fmaf_rn(fv, cb, iv * gv);
          hb = ov * fast_tanh(cb);

          if (g == 0) {
            op[k1] = ha;
            if (k1 < 4) op[16 + k1] = hb;
          }
          op += B_SZ * H_SZ;
        }
      }
      __syncthreads();
    }
  } else if ((wv & 1) == 0) {
    // ================= feeder-y (batch bb): Ys[s-2] = Wih1 . y0 ============
    v2f wy1[H_SZ / 2], wy2[H_SZ / 2];
#pragma unroll
    for (int t = 0; t < H_SZ / 2; ++t) {
      wy1[t].x = Wih1[j1 * H_SZ + 2 * t]; wy1[t].y = Wih1[j1 * H_SZ + 2 * t + 1];
      wy2[t].x = Wih1[j2 * H_SZ + 2 * t]; wy2[t].y = Wih1[j2 * H_SZ + 2 * t + 1];
    }

    for (int s = 0; s <= N_PH + 2; ++s) {
      if (s >= 2 && s <= N_PH + 1) {
        const int q = s - 2;
        for (int j = 0; j < P_LEN; ++j) {
          const int slot = (q * P_LEN + j) & (RING - 1);
          const float4* sp = (const float4*)hbuf[bb][slot];
          float4 y0 = sp[0], y1 = sp[1], y2 = sp[2], y3 = sp[3], y4 = sp[4];
          v2f yp[H_SZ / 2];
          yp[0].x = y0.x; yp[0].y = y0.y; yp[1].x = y0.z; yp[1].y = y0.w;
          yp[2].x = y1.x; yp[2].y = y1.y; yp[3].x = y1.z; yp[3].y = y1.w;
          yp[4].x = y2.x; yp[4].y = y2.y; yp[5].x = y2.z; yp[5].y = y2.w;
          yp[6].x = y3.x; yp[6].y = y3.y; yp[7].x = y3.z; yp[7].y = y3.w;
          yp[8].x = y4.x; yp[8].y = y4.y; yp[9].x = y4.z; yp[9].y = y4.w;

          v2f Y1a = zero2(), Y1b = zero2(), Y2a = zero2(), Y2b = zero2();
#pragma unroll
          for (int t = 0; t < H_SZ / 2; t += 2) {
            Y1a = fma2(wy1[t],     yp[t],     Y1a);
            Y2a = fma2(wy2[t],     yp[t],     Y2a);
            Y1b = fma2(wy1[t + 1], yp[t + 1], Y1b);
            Y2b = fma2(wy2[t + 1], yp[t + 1], Y2b);
          }
          v2f Y1 = Y1a + Y1b, Y2 = Y2a + Y2b;
          v2f Ys; Ys.x = Y1.x + Y1.y; Ys.y = Y2.x + Y2.y;
          ybuf[bb][slot][l] = Ys;
        }
      }
      __syncthreads();
    }
  } else {
    // ================= feeder-x (batch bb): Xs[s] = Wih0 . x ===============
    v2f wx1[C_IN / 2], wx2[C_IN / 2];
#pragma unroll
    for (int t = 0; t < C_IN / 2; ++t) {
      wx1[t].x = Wih0[j1 * C_IN + 2 * t]; wx1[t].y = Wih0[j1 * C_IN + 2 * t + 1];
      wx2[t].x = Wih0[j2 * C_IN + 2 * t]; wx2[t].y = Wih0[j2 * C_IN + 2 * t + 1];
    }

    const float* xl = x + (size_t)(l >> 3) * (B_SZ * C_IN) + b * C_IN + (l & 7);
    const size_t halfph = (size_t)8 * B_SZ * C_IN;
    const size_t phstr  = (size_t)P_LEN * B_SZ * C_IN;

    float cur0 = xl[0],     cur1 = xl[halfph];            // phase 0
    float nx0  = xl[phstr], nx1  = xl[phstr + halfph];    // phase 1

    for (int s = 0; s <= N_PH + 2; ++s) {
      if (s <= N_PH - 1) {
        xbuf[bb][l] = cur0; xbuf[bb][64 + l] = cur1;
        asm volatile("s_waitcnt lgkmcnt(0)" ::: "memory");
        float4 xc0 = ((const float4*)&xbuf[bb][0])[0];
        float4 xc1 = ((const float4*)&xbuf[bb][0])[1];
        for (int j = 0; j < P_LEN; ++j) {
          v2f xp[4];
          xp[0].x = xc0.x; xp[0].y = xc0.y; xp[1].x = xc0.z; xp[1].y = xc0.w;
          xp[2].x = xc1.x; xp[2].y = xc1.y; xp[3].x = xc1.z; xp[3].y = xc1.w;
          if (j + 1 < P_LEN) {
            xc0 = ((const float4*)&xbuf[bb][(j + 1) * C_IN])[0];
            xc1 = ((const float4*)&xbuf[bb][(j + 1) * C_IN])[1];
          }
          v2f X1 = zero2(), X2 = zero2();
#pragma unroll
          for (int t = 0; t < C_IN / 2; ++t) {
            X1 = fma2(wx1[t], xp[t], X1);
            X2 = fma2(wx2[t], xp[t], X2);
          }
          v2f Xs; Xs.x = X1.x + X1.y; Xs.y = X2.x + X2.y;
          xsbuf[bb][(s * P_LEN + j) & (RING - 1)][l] = Xs;
        }
        cur0 = nx0; cur1 = nx1;
        if (s + 2 <= N_PH - 1) {
          nx0 = xl[(size_t)(s + 2) * phstr];
          nx1 = xl[(size_t)(s + 2) * phstr + halfph];
        }
      }
      __syncthreads();
    }
  }
}

} // namespace

extern "C" void kernel_launch(void* const* d_in, const int* in_sizes, int n_in,
                              void* d_out, int out_size, void* d_ws, size_t ws_size,
                              hipStream_t stream) {
  const float* x    = (const float*)d_in[0];
  const float* Wih0 = (const float*)d_in[1];
  const float* Whh0 = (const float*)d_in[2];
  const float* bih0 = (const float*)d_in[3];
  const float* bhh0 = (const float*)d_in[4];
  const float* Wih1 = (const float*)d_in[5];
  const float* Whh1 = (const float*)d_in[6];
  const float* bih1 = (const float*)d_in[7];
  const float* bhh1 = (const float*)d_in[8];
  float* out = (float*)d_out;

  hipLaunchKernelGGL(lstm2_4role, dim3(B_SZ / 2), dim3(512), 0, stream,
                     x, Wih0, Whh0, bih0, bhh0, Wih1, Whh1, bih1, bhh1, out);
}